// Round 1
// baseline (1545.591 us; speedup 1.0000x reference)
//
#include <hip/hip_runtime.h>
#include <stdint.h>

// Problem dims
#define R_ 8
#define B_ 16
#define S_ 512
#define H_ 1024
#define E_ 32
#define P_ 4
#define M_ (B_*S_)          // 8192 rows
#define K_ (2*H_)           // 2048
#define N_ H_               // 1024

typedef __bf16 bf16x8 __attribute__((ext_vector_type(8)));
typedef float  f32x4  __attribute__((ext_vector_type(4)));

__device__ __forceinline__ uint16_t f2bf(float f){
  uint32_t u = __builtin_bit_cast(uint32_t, f);
  u += 0x7fffu + ((u >> 16) & 1u);          // RNE
  return (uint16_t)(u >> 16);
}
__device__ __forceinline__ float bf2f(uint16_t h){
  uint32_t u = ((uint32_t)h) << 16;
  return __builtin_bit_cast(float, u);
}

__device__ __forceinline__ void load_lds16(const void* g, void* l){
  __builtin_amdgcn_global_load_lds(
      (const __attribute__((address_space(1))) unsigned int*)g,
      (__attribute__((address_space(3))) unsigned int*)l, 16, 0, 0);
}

// ---------------- mask sum (token_mask.sum()) ----------------
__global__ void masksum_kernel(const float* __restrict__ tm, float* __restrict__ msum){
  __shared__ float red[16];
  int t = threadIdx.x;
  float s = 0.f;
  for (int i = t; i < B_*S_; i += 1024) s += tm[i];
  #pragma unroll
  for (int m = 32; m >= 1; m >>= 1) s += __shfl_xor(s, m, 64);
  if ((t & 63) == 0) red[t >> 6] = s;
  __syncthreads();
  if (t == 0){ float tot = 0.f; for (int i = 0; i < 16; i++) tot += red[i]; msum[0] = tot; }
}

// ---------------- precompute fp32 row-dots -------------------
// waves: [0,65536) sr rows -> sr_s (dot single_w[0:H]) and sr_m (dot multi_w[0:H])
//        [65536,73728) tok rows -> tok_s (dot single_w[H:2H])
//        [73728,81920) ent rows -> ent_m (dot multi_w[H:2H])
__global__ void dots_f32_kernel(const float* __restrict__ sr, const float* __restrict__ tok,
                                const float* __restrict__ ent, const float* __restrict__ sw,
                                const float* __restrict__ mw,
                                float* __restrict__ sr_s, float* __restrict__ sr_m,
                                float* __restrict__ tok_s, float* __restrict__ ent_m){
  int w = (int)((blockIdx.x * blockDim.x + threadIdx.x) >> 6);
  int lane = threadIdx.x & 63;
  if (w < R_*B_*S_){
    const float* rp = sr + (size_t)w * H_;
    float a0 = 0.f, a1 = 0.f;
    #pragma unroll
    for (int i = 0; i < 4; i++){
      int c = i*256 + lane*4;
      float4 v  = *(const float4*)(rp + c);
      float4 ws = *(const float4*)(sw + c);
      float4 wm = *(const float4*)(mw + c);
      a0 += v.x*ws.x + v.y*ws.y + v.z*ws.z + v.w*ws.w;
      a1 += v.x*wm.x + v.y*wm.y + v.z*wm.z + v.w*wm.w;
    }
    #pragma unroll
    for (int m = 32; m >= 1; m >>= 1){ a0 += __shfl_xor(a0, m, 64); a1 += __shfl_xor(a1, m, 64); }
    if (lane == 0){ sr_s[w] = a0; sr_m[w] = a1; }
  } else if (w < R_*B_*S_ + B_*S_){
    int rr = w - R_*B_*S_;
    const float* rp = tok + (size_t)rr * H_;
    float a0 = 0.f;
    #pragma unroll
    for (int i = 0; i < 4; i++){
      int c = i*256 + lane*4;
      float4 v  = *(const float4*)(rp + c);
      float4 ws = *(const float4*)(sw + H_ + c);
      a0 += v.x*ws.x + v.y*ws.y + v.z*ws.z + v.w*ws.w;
    }
    #pragma unroll
    for (int m = 32; m >= 1; m >>= 1) a0 += __shfl_xor(a0, m, 64);
    if (lane == 0) tok_s[rr] = a0;
  } else if (w < R_*B_*S_ + 2*B_*S_){
    int rr = w - R_*B_*S_ - B_*S_;
    const float* rp = ent + (size_t)rr * H_;
    float a0 = 0.f;
    #pragma unroll
    for (int i = 0; i < 4; i++){
      int c = i*256 + lane*4;
      float4 v  = *(const float4*)(rp + c);
      float4 wm = *(const float4*)(mw + H_ + c);
      a0 += v.x*wm.x + v.y*wm.y + v.z*wm.z + v.w*wm.w;
    }
    #pragma unroll
    for (int m = 32; m >= 1; m >>= 1) a0 += __shfl_xor(a0, m, 64);
    if (lane == 0) ent_m[rr] = a0;
  }
}

// ---------------- transpose answer_w -> bf16 [N][K] ----------
__global__ void trans_w_kernel(const float* __restrict__ W, uint16_t* __restrict__ Wt){
  __shared__ float tile[64][65];
  int k0 = blockIdx.x * 64, n0 = blockIdx.y * 64;
  int t = threadIdx.x;
  #pragma unroll
  for (int i = 0; i < 16; i++){
    int lin = i*256 + t, kk = lin >> 6, nn = lin & 63;
    tile[kk][nn] = W[(size_t)(k0+kk) * N_ + (n0+nn)];
  }
  __syncthreads();
  #pragma unroll
  for (int i = 0; i < 16; i++){
    int lin = i*256 + t, nn = lin >> 6, kk = lin & 63;
    Wt[(size_t)(n0+nn) * K_ + (k0+kk)] = f2bf(tile[kk][nn]);
  }
}

// ---------------- tok fp32 -> bf16 ---------------------------
__global__ void cvt_tok_kernel(const float* __restrict__ tok, uint16_t* __restrict__ tokbf){
  int i8 = blockIdx.x * blockDim.x + threadIdx.x;
  int base = i8 * 8;
  float4 v0 = *(const float4*)(tok + base);
  float4 v1 = *(const float4*)(tok + base + 4);
  union { uint4 v4; uint16_t u[8]; } o;
  o.u[0]=f2bf(v0.x); o.u[1]=f2bf(v0.y); o.u[2]=f2bf(v0.z); o.u[3]=f2bf(v0.w);
  o.u[4]=f2bf(v1.x); o.u[5]=f2bf(v1.y); o.u[6]=f2bf(v1.z); o.u[7]=f2bf(v1.w);
  *(uint4*)(tokbf + base) = o.v4;
}

// ---------------- curr = tok_bf * arg[row] -------------------
__global__ void curr_kernel(const uint16_t* __restrict__ tokbf, const float* __restrict__ arg,
                            uint16_t* __restrict__ currbf){
  int i8 = blockIdx.x * blockDim.x + threadIdx.x;
  int base = i8 * 8;
  float a = arg[base >> 10];
  union { uint4 v4; uint16_t u[8]; } in, o;
  in.v4 = *(const uint4*)(tokbf + base);
  #pragma unroll
  for (int j = 0; j < 8; j++) o.u[j] = f2bf(bf2f(in.u[j]) * a);
  *(uint4*)(currbf + base) = o.v4;
}

// ---------------- middle: softmax/scatter/spans/merge/loss ---
__global__ __launch_bounds__(1024) void middle_kernel(
    int r,
    const float* __restrict__ sr_s, const float* __restrict__ sr_m,
    const float* __restrict__ tok_s, const float* __restrict__ ent_m,
    const float* __restrict__ pre_s, const float* __restrict__ pre_m,
    const float* __restrict__ sb, const float* __restrict__ mb,
    const int* __restrict__ c2t, const int* __restrict__ e2t,
    const int* __restrict__ spans, const int* __restrict__ labels,
    const float* __restrict__ msum,
    float* __restrict__ out, float* __restrict__ arg)
{
  __shared__ float pta[B_*S_];     // scatter target, becomes `merged` in place (32KB)
  __shared__ float es[B_*E_];      // entity scores (2KB)
  __shared__ int   spn[B_*E_*P_*2];// spans (16KB)
  const int t = threadIdx.x;

  for (int i = t; i < B_*S_; i += 1024) pta[i] = 0.f;
  if (t < B_*E_) es[t] = 0.f;
  for (int i = t; i < B_*E_*P_*2; i += 1024) spn[i] = spans[i];
  __syncthreads();

  const float sbv = sb[0], mbv = mb[0];
  if (t < S_){
    int s = t;
    float sl[16], ml[16];
    float smax = -1e30f, mmax = -1e30f;
    #pragma unroll
    for (int b = 0; b < 16; b++){
      int bs = b*S_ + s;
      float x = sr_s[(r*B_ + b)*S_ + s] + tok_s[bs] + pre_s[bs] + sbv;
      float y = sr_m[(r*B_ + b)*S_ + s] + ent_m[bs] + pre_m[bs] + mbv;
      sl[b] = x; ml[b] = y;
      smax = fmaxf(smax, x); mmax = fmaxf(mmax, y);
    }
    float ssum = 0.f, msv = 0.f;
    #pragma unroll
    for (int b = 0; b < 16; b++){ ssum += __expf(sl[b]-smax); msv += __expf(ml[b]-mmax); }
    float sinv = 1.f/ssum, minv = 1.f/msv;
    #pragma unroll
    for (int b = 0; b < 16; b++){
      int bs = b*S_ + s;
      float spv = __expf(sl[b]-smax) * sinv;
      int c = c2t[bs];
      if (c >= 0) atomicAdd(&pta[b*S_ + c], spv);
      float mpv = __expf(ml[b]-mmax) * minv;
      int e = e2t[bs];
      if (e >= 0) atomicAdd(&es[b*E_ + e], mpv);
    }
  }
  __syncthreads();

  // merge: pred_entity_ids from spans, max with scatter result, emit merged
  #pragma unroll
  for (int i = 0; i < 8; i++){
    int idx = i*1024 + t;
    int b = idx >> 9, s = idx & 511;
    float pei = 0.f;
    const int* spb = spn + b*(E_*P_*2);
    #pragma unroll
    for (int e = 0; e < E_; e++){
      float sc = es[b*E_ + e];
      #pragma unroll
      for (int p = 0; p < P_; p++){
        int st = spb[e*8 + p*2], en = spb[e*8 + p*2 + 1];
        if (s >= st && s < en) pei += sc;
      }
    }
    float m = fmaxf(pta[idx], pei);
    pta[idx] = m;                       // pta is now `merged`
    out[1 + r*(B_*S_) + idx] = m;
  }
  __syncthreads();

  // arg gather
  #pragma unroll
  for (int i = 0; i < 8; i++){
    int idx = i*1024 + t;
    int c = c2t[idx];
    arg[idx] = (c >= 0) ? pta[(idx & ~511) + c] : 0.f;
  }

  // loss: wave w handles row b=w: nll_b = lse(merged[b,:]) - merged[b,label]
  int wid = t >> 6, lane = t & 63;
  {
    int b = wid;
    float mx = -1e30f;
    #pragma unroll
    for (int i = 0; i < 8; i++) mx = fmaxf(mx, pta[b*S_ + i*64 + lane]);
    #pragma unroll
    for (int m = 32; m >= 1; m >>= 1) mx = fmaxf(mx, __shfl_xor(mx, m, 64));
    float se = 0.f;
    #pragma unroll
    for (int i = 0; i < 8; i++) se += __expf(pta[b*S_ + i*64 + lane] - mx);
    #pragma unroll
    for (int m = 32; m >= 1; m >>= 1) se += __shfl_xor(se, m, 64);
    if (lane == 0){
      float lse = mx + __logf(se);
      int lbl = labels[r*B_ + b];
      float nll = lse - pta[b*S_ + lbl];
      atomicAdd(out, nll * msum[0] * (1.0f/16.0f));
    }
  }
}

// ---------------- GEMM: new_pre = [curr|pre] @ Wt^T + bias ---
// A1=curr_bf [M][H], A2=pre_bf [M][H], Bt = answer_w^T bf16 [N][K]
// 128x128 tile, BK=32, 4 waves (2x2), 16x16x32 MFMA (m97 structure)
__global__ __launch_bounds__(256) void gemm_kernel(
    const uint16_t* __restrict__ A1, const uint16_t* __restrict__ A2,
    const uint16_t* __restrict__ Bt, const float* __restrict__ bias,
    uint16_t* __restrict__ Out)
{
  __shared__ uint16_t lA[128*32];
  __shared__ uint16_t lB[128*32];
  const int tid = threadIdx.x;
  const int lane = tid & 63, wid = tid >> 6;
  const int row0 = blockIdx.y * 128, col0 = blockIdx.x * 128;
  const int wm = wid >> 1, wn = wid & 1;

  f32x4 acc[4][4] = {};

  const int c0 = wid*64 + lane;          // staging chunk (16B) index, issue 0
  const int c1 = 256 + c0;               // issue 1
  const int r0c = c0 >> 2, k0c = (c0 & 3) * 8;
  const int r1c = c1 >> 2, k1c = (c1 & 3) * 8;

  for (int kt = 0; kt < K_/32; ++kt){
    const int kg = kt * 32;
    const uint16_t* Ab = (kg < H_) ? (A1 + kg) : (A2 + (kg - H_));
    const uint16_t* Bb = Bt + kg;
    load_lds16(Ab + (size_t)(row0 + r0c)*H_ + k0c, lA + (size_t)(wid*64)*8);
    load_lds16(Ab + (size_t)(row0 + r1c)*H_ + k1c, lA + (size_t)(256 + wid*64)*8);
    load_lds16(Bb + (size_t)(col0 + r0c)*K_ + k0c, lB + (size_t)(wid*64)*8);
    load_lds16(Bb + (size_t)(col0 + r1c)*K_ + k1c, lB + (size_t)(256 + wid*64)*8);
    __syncthreads();

    const int kof = (lane >> 4) * 8;
    bf16x8 a[4], b[4];
    #pragma unroll
    for (int i = 0; i < 4; i++)
      a[i] = *reinterpret_cast<const bf16x8*>(&lA[(wm*64 + i*16 + (lane & 15))*32 + kof]);
    #pragma unroll
    for (int j = 0; j < 4; j++)
      b[j] = *reinterpret_cast<const bf16x8*>(&lB[(wn*64 + j*16 + (lane & 15))*32 + kof]);
    #pragma unroll
    for (int i = 0; i < 4; i++)
      #pragma unroll
      for (int j = 0; j < 4; j++)
        acc[i][j] = __builtin_amdgcn_mfma_f32_16x16x32_bf16(a[i], b[j], acc[i][j], 0, 0, 0);
    __syncthreads();
  }

  // epilogue: +bias, cast bf16, store
  #pragma unroll
  for (int m = 0; m < 4; m++){
    int rbase = row0 + wm*64 + m*16 + ((lane >> 4) << 2);
    #pragma unroll
    for (int n = 0; n < 4; n++){
      int col = col0 + wn*64 + n*16 + (lane & 15);
      float bc = bias[col];
      #pragma unroll
      for (int j = 0; j < 4; j++){
        float v = acc[m][n][j] + bc;
        Out[(size_t)(rbase + j)*N_ + col] = f2bf(v);
      }
    }
  }
}

// ---------------- pre_s/pre_m from new pre (bf16 rows) -------
__global__ void dots_pre_kernel(const uint16_t* __restrict__ pre, const float* __restrict__ sw,
                                const float* __restrict__ mw,
                                float* __restrict__ pre_s, float* __restrict__ pre_m){
  int w = (int)((blockIdx.x * blockDim.x + threadIdx.x) >> 6);   // row 0..8191
  int lane = threadIdx.x & 63;
  const uint16_t* rp = pre + (size_t)w * H_;
  float a0 = 0.f, a1 = 0.f;
  #pragma unroll
  for (int h = 0; h < 2; h++){
    int c = h*512 + lane*8;
    union { uint4 v4; uint16_t u[8]; } v;
    v.v4 = *(const uint4*)(rp + c);
    float f[8];
    #pragma unroll
    for (int j = 0; j < 8; j++) f[j] = bf2f(v.u[j]);
    const float* wsp = sw + 2*H_ + c;
    const float* wmp = mw + 2*H_ + c;
    float4 s0 = *(const float4*)wsp, s1 = *(const float4*)(wsp+4);
    float4 m0 = *(const float4*)wmp, m1 = *(const float4*)(wmp+4);
    a0 += f[0]*s0.x + f[1]*s0.y + f[2]*s0.z + f[3]*s0.w
        + f[4]*s1.x + f[5]*s1.y + f[6]*s1.z + f[7]*s1.w;
    a1 += f[0]*m0.x + f[1]*m0.y + f[2]*m0.z + f[3]*m0.w
        + f[4]*m1.x + f[5]*m1.y + f[6]*m1.z + f[7]*m1.w;
  }
  #pragma unroll
  for (int m = 32; m >= 1; m >>= 1){ a0 += __shfl_xor(a0, m, 64); a1 += __shfl_xor(a1, m, 64); }
  if (lane == 0){ pre_s[w] = a0; pre_m[w] = a1; }
}

extern "C" void kernel_launch(void* const* d_in, const int* in_sizes, int n_in,
                              void* d_out, int out_size, void* d_ws, size_t ws_size,
                              hipStream_t stream){
  (void)in_sizes; (void)n_in; (void)out_size;
  const int*   labels = (const int*)  d_in[0];
  const float* sr     = (const float*)d_in[1];
  const float* tok    = (const float*)d_in[2];
  const float* ent    = (const float*)d_in[3];
  const float* tmask  = (const float*)d_in[4];
  // d_in[5] entity_mask unused by reference
  const int*   spans  = (const int*)  d_in[6];
  const int*   c2t    = (const int*)  d_in[7];
  const int*   e2t    = (const int*)  d_in[8];
  const float* sw     = (const float*)d_in[9];
  const float* sb     = (const float*)d_in[10];
  const float* mw     = (const float*)d_in[11];
  const float* mb     = (const float*)d_in[12];
  const float* aw     = (const float*)d_in[13];
  const float* ab     = (const float*)d_in[14];
  float* out = (float*)d_out;
  char*  ws  = (char*)d_ws;

  size_t o = 0;
  auto take = [&](size_t bytes){ size_t c = o; o += (bytes + 255) & ~(size_t)255; return c; };
  float*    sr_s   = (float*)   (ws + take((size_t)R_*B_*S_*4));
  float*    sr_m   = (float*)   (ws + take((size_t)R_*B_*S_*4));
  float*    tok_s  = (float*)   (ws + take((size_t)B_*S_*4));
  float*    ent_m  = (float*)   (ws + take((size_t)B_*S_*4));
  float*    pre_s  = (float*)   (ws + take((size_t)B_*S_*4));
  float*    pre_m  = (float*)   (ws + take((size_t)B_*S_*4));
  float*    argb   = (float*)   (ws + take((size_t)B_*S_*4));
  float*    msum   = (float*)   (ws + take(256));
  uint16_t* tok_bf = (uint16_t*)(ws + take((size_t)M_*H_*2));
  uint16_t* w_t    = (uint16_t*)(ws + take((size_t)N_*K_*2));
  uint16_t* currbf = (uint16_t*)(ws + take((size_t)M_*H_*2));
  uint16_t* pre0   = (uint16_t*)(ws + take((size_t)M_*H_*2));
  uint16_t* pre1   = (uint16_t*)(ws + take((size_t)M_*H_*2));
  (void)ws_size;

  hipMemsetAsync(out, 0, sizeof(float), stream);                 // loss accumulator
  hipMemsetAsync(pre0, 0, (size_t)M_*H_*2, stream);              // pre_answer(r=0) = 0
  hipMemsetAsync(pre_s, 0, (size_t)B_*S_*4, stream);
  hipMemsetAsync(pre_m, 0, (size_t)B_*S_*4, stream);

  masksum_kernel<<<1, 1024, 0, stream>>>(tmask, msum);
  {
    int waves = R_*B_*S_ + 2*B_*S_;            // 81920
    dots_f32_kernel<<<waves/4, 256, 0, stream>>>(sr, tok, ent, sw, mw, sr_s, sr_m, tok_s, ent_m);
  }
  trans_w_kernel<<<dim3(K_/64, N_/64), 256, 0, stream>>>(aw, w_t);
  cvt_tok_kernel<<<(M_*H_/8)/256, 256, 0, stream>>>(tok, tok_bf);

  uint16_t* preA = pre0;
  uint16_t* preB = pre1;
  for (int r = 0; r < R_; r++){
    middle_kernel<<<1, 1024, 0, stream>>>(r, sr_s, sr_m, tok_s, ent_m, pre_s, pre_m,
                                          sb, mb, c2t, e2t, spans, labels, msum, out, argb);
    if (r < R_-1){
      curr_kernel<<<(M_*H_/8)/256, 256, 0, stream>>>(tok_bf, argb, currbf);
      gemm_kernel<<<dim3(N_/128, M_/128), 256, 0, stream>>>(currbf, preA, w_t, ab, preB);
      dots_pre_kernel<<<(M_*64)/256, 256, 0, stream>>>(preB, sw, mw, pre_s, pre_m);
      uint16_t* tmp = preA; preA = preB; preB = tmp;
    }
  }
}

// Round 2
// 728.849 us; speedup vs baseline: 2.1206x; 2.1206x over previous
//
#include <hip/hip_runtime.h>
#include <stdint.h>

// Problem dims
#define R_ 8
#define B_ 16
#define S_ 512
#define H_ 1024
#define E_ 32
#define P_ 4
#define M_ (B_*S_)          // 8192 rows
#define K_ (2*H_)           // 2048
#define N_ H_               // 1024

typedef __bf16 bf16x8 __attribute__((ext_vector_type(8)));
typedef float  f32x4  __attribute__((ext_vector_type(4)));

__device__ __forceinline__ uint16_t f2bf(float f){
  uint32_t u = __builtin_bit_cast(uint32_t, f);
  u += 0x7fffu + ((u >> 16) & 1u);          // RNE
  return (uint16_t)(u >> 16);
}
__device__ __forceinline__ float bf2f(uint16_t h){
  uint32_t u = ((uint32_t)h) << 16;
  return __builtin_bit_cast(float, u);
}

__device__ __forceinline__ void load_lds16(const void* g, void* l){
  __builtin_amdgcn_global_load_lds(
      (const __attribute__((address_space(1))) unsigned int*)g,
      (__attribute__((address_space(3))) unsigned int*)l, 16, 0, 0);
}

// ---------------- mask sum (token_mask.sum()) ----------------
__global__ void masksum_kernel(const float* __restrict__ tm, float* __restrict__ msum){
  __shared__ float red[16];
  int t = threadIdx.x;
  float s = 0.f;
  for (int i = t; i < B_*S_; i += 1024) s += tm[i];
  #pragma unroll
  for (int m = 32; m >= 1; m >>= 1) s += __shfl_xor(s, m, 64);
  if ((t & 63) == 0) red[t >> 6] = s;
  __syncthreads();
  if (t == 0){ float tot = 0.f; for (int i = 0; i < 16; i++) tot += red[i]; msum[0] = tot; }
}

// ---------------- precompute fp32 row-dots -------------------
__global__ void dots_f32_kernel(const float* __restrict__ sr, const float* __restrict__ tok,
                                const float* __restrict__ ent, const float* __restrict__ sw,
                                const float* __restrict__ mw,
                                float* __restrict__ sr_s, float* __restrict__ sr_m,
                                float* __restrict__ tok_s, float* __restrict__ ent_m){
  int w = (int)((blockIdx.x * blockDim.x + threadIdx.x) >> 6);
  int lane = threadIdx.x & 63;
  if (w < R_*B_*S_){
    const float* rp = sr + (size_t)w * H_;
    float a0 = 0.f, a1 = 0.f;
    #pragma unroll
    for (int i = 0; i < 4; i++){
      int c = i*256 + lane*4;
      float4 v  = *(const float4*)(rp + c);
      float4 ws = *(const float4*)(sw + c);
      float4 wm = *(const float4*)(mw + c);
      a0 += v.x*ws.x + v.y*ws.y + v.z*ws.z + v.w*ws.w;
      a1 += v.x*wm.x + v.y*wm.y + v.z*wm.z + v.w*wm.w;
    }
    #pragma unroll
    for (int m = 32; m >= 1; m >>= 1){ a0 += __shfl_xor(a0, m, 64); a1 += __shfl_xor(a1, m, 64); }
    if (lane == 0){ sr_s[w] = a0; sr_m[w] = a1; }
  } else if (w < R_*B_*S_ + B_*S_){
    int rr = w - R_*B_*S_;
    const float* rp = tok + (size_t)rr * H_;
    float a0 = 0.f;
    #pragma unroll
    for (int i = 0; i < 4; i++){
      int c = i*256 + lane*4;
      float4 v  = *(const float4*)(rp + c);
      float4 ws = *(const float4*)(sw + H_ + c);
      a0 += v.x*ws.x + v.y*ws.y + v.z*ws.z + v.w*ws.w;
    }
    #pragma unroll
    for (int m = 32; m >= 1; m >>= 1) a0 += __shfl_xor(a0, m, 64);
    if (lane == 0) tok_s[rr] = a0;
  } else if (w < R_*B_*S_ + 2*B_*S_){
    int rr = w - R_*B_*S_ - B_*S_;
    const float* rp = ent + (size_t)rr * H_;
    float a0 = 0.f;
    #pragma unroll
    for (int i = 0; i < 4; i++){
      int c = i*256 + lane*4;
      float4 v  = *(const float4*)(rp + c);
      float4 wm = *(const float4*)(mw + H_ + c);
      a0 += v.x*wm.x + v.y*wm.y + v.z*wm.z + v.w*wm.w;
    }
    #pragma unroll
    for (int m = 32; m >= 1; m >>= 1) a0 += __shfl_xor(a0, m, 64);
    if (lane == 0) ent_m[rr] = a0;
  }
}

// ---------------- transpose answer_w -> bf16 [N][K] ----------
__global__ void trans_w_kernel(const float* __restrict__ W, uint16_t* __restrict__ Wt){
  __shared__ float tile[64][65];
  int k0 = blockIdx.x * 64, n0 = blockIdx.y * 64;
  int t = threadIdx.x;
  #pragma unroll
  for (int i = 0; i < 16; i++){
    int lin = i*256 + t, kk = lin >> 6, nn = lin & 63;
    tile[kk][nn] = W[(size_t)(k0+kk) * N_ + (n0+nn)];
  }
  __syncthreads();
  #pragma unroll
  for (int i = 0; i < 16; i++){
    int lin = i*256 + t, nn = lin >> 6, kk = lin & 63;
    Wt[(size_t)(n0+nn) * K_ + (k0+kk)] = f2bf(tile[kk][nn]);
  }
}

// ---------------- tok fp32 -> bf16 ---------------------------
__global__ void cvt_tok_kernel(const float* __restrict__ tok, uint16_t* __restrict__ tokbf){
  int i8 = blockIdx.x * blockDim.x + threadIdx.x;
  int base = i8 * 8;
  float4 v0 = *(const float4*)(tok + base);
  float4 v1 = *(const float4*)(tok + base + 4);
  union { uint4 v4; uint16_t u[8]; } o;
  o.u[0]=f2bf(v0.x); o.u[1]=f2bf(v0.y); o.u[2]=f2bf(v0.z); o.u[3]=f2bf(v0.w);
  o.u[4]=f2bf(v1.x); o.u[5]=f2bf(v1.y); o.u[6]=f2bf(v1.z); o.u[7]=f2bf(v1.w);
  *(uint4*)(tokbf + base) = o.v4;
}

// ---------------- curr = tok_bf * arg[row] -------------------
__global__ void curr_kernel(const uint16_t* __restrict__ tokbf, const float* __restrict__ arg,
                            uint16_t* __restrict__ currbf){
  int i8 = blockIdx.x * blockDim.x + threadIdx.x;
  int base = i8 * 8;
  float a = arg[base >> 10];
  union { uint4 v4; uint16_t u[8]; } in, o;
  in.v4 = *(const uint4*)(tokbf + base);
  #pragma unroll
  for (int j = 0; j < 8; j++) o.u[j] = f2bf(bf2f(in.u[j]) * a);
  *(uint4*)(currbf + base) = o.v4;
}

// ---------------- K1: batch-softmax + scatter (global atomics) ----
// grid 8 x 64 threads, one thread per s. pta_g/es_g pre-zeroed per role.
__global__ __launch_bounds__(64) void softmax_scatter_kernel(
    int r,
    const float* __restrict__ sr_s, const float* __restrict__ sr_m,
    const float* __restrict__ tok_s, const float* __restrict__ ent_m,
    const float* __restrict__ pre_s, const float* __restrict__ pre_m,
    const float* __restrict__ sb, const float* __restrict__ mb,
    const int* __restrict__ c2t, const int* __restrict__ e2t,
    float* __restrict__ pta_g, float* __restrict__ es_g)
{
  int s = blockIdx.x * 64 + threadIdx.x;
  const float sbv = sb[0], mbv = mb[0];
  float sl[16], ml[16];
  float smax = -1e30f, mmax = -1e30f;
  #pragma unroll
  for (int b = 0; b < 16; b++){
    int bs = b*S_ + s;
    float x = sr_s[(r*B_ + b)*S_ + s] + tok_s[bs] + pre_s[bs] + sbv;
    float y = sr_m[(r*B_ + b)*S_ + s] + ent_m[bs] + pre_m[bs] + mbv;
    sl[b] = x; ml[b] = y;
    smax = fmaxf(smax, x); mmax = fmaxf(mmax, y);
  }
  float ssum = 0.f, msv = 0.f;
  #pragma unroll
  for (int b = 0; b < 16; b++){ ssum += __expf(sl[b]-smax); msv += __expf(ml[b]-mmax); }
  float sinv = 1.f/ssum, minv = 1.f/msv;
  #pragma unroll
  for (int b = 0; b < 16; b++){
    int bs = b*S_ + s;
    float spv = __expf(sl[b]-smax) * sinv;
    int c = c2t[bs];
    if (c >= 0) atomicAdd(&pta_g[b*S_ + c], spv);
    float mpv = __expf(ml[b]-mmax) * minv;
    int e = e2t[bs];
    if (e >= 0) atomicAdd(&es_g[b*E_ + e], mpv);
  }
}

// ---------------- K2: span-cover merge + arg + loss ----------
// grid 16 blocks (one per b) x 512 threads (one per s)
__global__ __launch_bounds__(512) void merge_loss_kernel(
    int r,
    const float* __restrict__ pta_g, const float* __restrict__ es_g,
    const int* __restrict__ c2t, const int* __restrict__ spans,
    const int* __restrict__ labels, const float* __restrict__ msum,
    float* __restrict__ out, float* __restrict__ arg)
{
  __shared__ float es[E_];
  __shared__ int   spn[E_*P_*2];
  __shared__ float merged[S_];
  __shared__ float red[8];
  const int b = blockIdx.x;
  const int t = threadIdx.x;

  if (t < E_) es[t] = es_g[b*E_ + t];
  if (t < E_*P_*2) spn[t] = spans[b*(E_*P_*2) + t];
  __syncthreads();

  // span coverage + max-merge
  float pei = 0.f;
  #pragma unroll
  for (int e = 0; e < E_; e++){
    float sc = es[e];
    #pragma unroll
    for (int p = 0; p < P_; p++){
      int st = spn[e*8 + p*2], en = spn[e*8 + p*2 + 1];
      if (t >= st && t < en) pei += sc;
    }
  }
  float m = fmaxf(pta_g[b*S_ + t], pei);
  merged[t] = m;
  out[1 + r*(B_*S_) + b*S_ + t] = m;
  __syncthreads();

  // arg gather
  {
    int c = c2t[b*S_ + t];
    arg[b*S_ + t] = (c >= 0) ? merged[c] : 0.f;
  }

  // CE loss for this row: lse(merged) - merged[label]
  int wid = t >> 6, lane = t & 63;
  float mx = m;
  #pragma unroll
  for (int k = 32; k >= 1; k >>= 1) mx = fmaxf(mx, __shfl_xor(mx, k, 64));
  if (lane == 0) red[wid] = mx;
  __syncthreads();
  float gmx = red[0];
  #pragma unroll
  for (int i = 1; i < 8; i++) gmx = fmaxf(gmx, red[i]);
  float se = __expf(m - gmx);
  #pragma unroll
  for (int k = 32; k >= 1; k >>= 1) se += __shfl_xor(se, k, 64);
  __syncthreads();
  if (lane == 0) red[wid] = se;
  __syncthreads();
  if (t == 0){
    float tot = 0.f;
    #pragma unroll
    for (int i = 0; i < 8; i++) tot += red[i];
    float lse = gmx + __logf(tot);
    int lbl = labels[r*B_ + b];
    float nll = lse - merged[lbl];
    atomicAdd(out, nll * msum[0] * (1.0f/16.0f));
  }
}

// ---------------- GEMM: new_pre = [curr|pre] @ Wt^T + bias ---
__global__ __launch_bounds__(256) void gemm_kernel(
    const uint16_t* __restrict__ A1, const uint16_t* __restrict__ A2,
    const uint16_t* __restrict__ Bt, const float* __restrict__ bias,
    uint16_t* __restrict__ Out)
{
  __shared__ uint16_t lA[128*32];
  __shared__ uint16_t lB[128*32];
  const int tid = threadIdx.x;
  const int lane = tid & 63, wid = tid >> 6;
  const int row0 = blockIdx.y * 128, col0 = blockIdx.x * 128;
  const int wm = wid >> 1, wn = wid & 1;

  f32x4 acc[4][4] = {};

  const int c0 = wid*64 + lane;
  const int c1 = 256 + c0;
  const int r0c = c0 >> 2, k0c = (c0 & 3) * 8;
  const int r1c = c1 >> 2, k1c = (c1 & 3) * 8;

  for (int kt = 0; kt < K_/32; ++kt){
    const int kg = kt * 32;
    const uint16_t* Ab = (kg < H_) ? (A1 + kg) : (A2 + (kg - H_));
    const uint16_t* Bb = Bt + kg;
    load_lds16(Ab + (size_t)(row0 + r0c)*H_ + k0c, lA + (size_t)(wid*64)*8);
    load_lds16(Ab + (size_t)(row0 + r1c)*H_ + k1c, lA + (size_t)(256 + wid*64)*8);
    load_lds16(Bb + (size_t)(col0 + r0c)*K_ + k0c, lB + (size_t)(wid*64)*8);
    load_lds16(Bb + (size_t)(col0 + r1c)*K_ + k1c, lB + (size_t)(256 + wid*64)*8);
    __syncthreads();

    const int kof = (lane >> 4) * 8;
    bf16x8 a[4], b[4];
    #pragma unroll
    for (int i = 0; i < 4; i++)
      a[i] = *reinterpret_cast<const bf16x8*>(&lA[(wm*64 + i*16 + (lane & 15))*32 + kof]);
    #pragma unroll
    for (int j = 0; j < 4; j++)
      b[j] = *reinterpret_cast<const bf16x8*>(&lB[(wn*64 + j*16 + (lane & 15))*32 + kof]);
    #pragma unroll
    for (int i = 0; i < 4; i++)
      #pragma unroll
      for (int j = 0; j < 4; j++)
        acc[i][j] = __builtin_amdgcn_mfma_f32_16x16x32_bf16(a[i], b[j], acc[i][j], 0, 0, 0);
    __syncthreads();
  }

  #pragma unroll
  for (int m = 0; m < 4; m++){
    int rbase = row0 + wm*64 + m*16 + ((lane >> 4) << 2);
    #pragma unroll
    for (int n = 0; n < 4; n++){
      int col = col0 + wn*64 + n*16 + (lane & 15);
      float bc = bias[col];
      #pragma unroll
      for (int j = 0; j < 4; j++){
        float v = acc[m][n][j] + bc;
        Out[(size_t)(rbase + j)*N_ + col] = f2bf(v);
      }
    }
  }
}

// ---------------- pre_s/pre_m from new pre (bf16 rows) -------
__global__ void dots_pre_kernel(const uint16_t* __restrict__ pre, const float* __restrict__ sw,
                                const float* __restrict__ mw,
                                float* __restrict__ pre_s, float* __restrict__ pre_m){
  int w = (int)((blockIdx.x * blockDim.x + threadIdx.x) >> 6);   // row 0..8191
  int lane = threadIdx.x & 63;
  const uint16_t* rp = pre + (size_t)w * H_;
  float a0 = 0.f, a1 = 0.f;
  #pragma unroll
  for (int h = 0; h < 2; h++){
    int c = h*512 + lane*8;
    union { uint4 v4; uint16_t u[8]; } v;
    v.v4 = *(const uint4*)(rp + c);
    float f[8];
    #pragma unroll
    for (int j = 0; j < 8; j++) f[j] = bf2f(v.u[j]);
    const float* wsp = sw + 2*H_ + c;
    const float* wmp = mw + 2*H_ + c;
    float4 s0 = *(const float4*)wsp, s1 = *(const float4*)(wsp+4);
    float4 m0 = *(const float4*)wmp, m1 = *(const float4*)(wmp+4);
    a0 += f[0]*s0.x + f[1]*s0.y + f[2]*s0.z + f[3]*s0.w
        + f[4]*s1.x + f[5]*s1.y + f[6]*s1.z + f[7]*s1.w;
    a1 += f[0]*m0.x + f[1]*m0.y + f[2]*m0.z + f[3]*m0.w
        + f[4]*m1.x + f[5]*m1.y + f[6]*m1.z + f[7]*m1.w;
  }
  #pragma unroll
  for (int m = 32; m >= 1; m >>= 1){ a0 += __shfl_xor(a0, m, 64); a1 += __shfl_xor(a1, m, 64); }
  if (lane == 0){ pre_s[w] = a0; pre_m[w] = a1; }
}

extern "C" void kernel_launch(void* const* d_in, const int* in_sizes, int n_in,
                              void* d_out, int out_size, void* d_ws, size_t ws_size,
                              hipStream_t stream){
  (void)in_sizes; (void)n_in; (void)out_size;
  const int*   labels = (const int*)  d_in[0];
  const float* sr     = (const float*)d_in[1];
  const float* tok    = (const float*)d_in[2];
  const float* ent    = (const float*)d_in[3];
  const float* tmask  = (const float*)d_in[4];
  const int*   spans  = (const int*)  d_in[6];
  const int*   c2t    = (const int*)  d_in[7];
  const int*   e2t    = (const int*)  d_in[8];
  const float* sw     = (const float*)d_in[9];
  const float* sb     = (const float*)d_in[10];
  const float* mw     = (const float*)d_in[11];
  const float* mb     = (const float*)d_in[12];
  const float* aw     = (const float*)d_in[13];
  const float* ab     = (const float*)d_in[14];
  float* out = (float*)d_out;
  char*  ws  = (char*)d_ws;

  size_t o = 0;
  auto take = [&](size_t bytes){ size_t c = o; o += (bytes + 255) & ~(size_t)255; return c; };
  float*    sr_s   = (float*)   (ws + take((size_t)R_*B_*S_*4));
  float*    sr_m   = (float*)   (ws + take((size_t)R_*B_*S_*4));
  float*    tok_s  = (float*)   (ws + take((size_t)B_*S_*4));
  float*    ent_m  = (float*)   (ws + take((size_t)B_*S_*4));
  float*    pre_s  = (float*)   (ws + take((size_t)B_*S_*4));
  float*    pre_m  = (float*)   (ws + take((size_t)B_*S_*4));
  float*    argb   = (float*)   (ws + take((size_t)B_*S_*4));
  // pta_g (B*S) and es_g (B*E) contiguous for a single per-role memset
  float*    pta_g  = (float*)   (ws + take((size_t)(B_*S_ + B_*E_)*4));
  float*    es_g   = pta_g + B_*S_;
  float*    msum   = (float*)   (ws + take(256));
  uint16_t* tok_bf = (uint16_t*)(ws + take((size_t)M_*H_*2));
  uint16_t* w_t    = (uint16_t*)(ws + take((size_t)N_*K_*2));
  uint16_t* currbf = (uint16_t*)(ws + take((size_t)M_*H_*2));
  uint16_t* pre0   = (uint16_t*)(ws + take((size_t)M_*H_*2));
  uint16_t* pre1   = (uint16_t*)(ws + take((size_t)M_*H_*2));
  (void)ws_size;

  hipMemsetAsync(out, 0, sizeof(float), stream);                 // loss accumulator
  hipMemsetAsync(pre0, 0, (size_t)M_*H_*2, stream);              // pre_answer(r=0) = 0
  hipMemsetAsync(pre_s, 0, (size_t)B_*S_*4, stream);
  hipMemsetAsync(pre_m, 0, (size_t)B_*S_*4, stream);

  masksum_kernel<<<1, 1024, 0, stream>>>(tmask, msum);
  {
    int waves = R_*B_*S_ + 2*B_*S_;            // 81920
    dots_f32_kernel<<<waves/4, 256, 0, stream>>>(sr, tok, ent, sw, mw, sr_s, sr_m, tok_s, ent_m);
  }
  trans_w_kernel<<<dim3(K_/64, N_/64), 256, 0, stream>>>(aw, w_t);
  cvt_tok_kernel<<<(M_*H_/8)/256, 256, 0, stream>>>(tok, tok_bf);

  uint16_t* preA = pre0;
  uint16_t* preB = pre1;
  for (int r = 0; r < R_; r++){
    hipMemsetAsync(pta_g, 0, (size_t)(B_*S_ + B_*E_)*4, stream);
    softmax_scatter_kernel<<<8, 64, 0, stream>>>(r, sr_s, sr_m, tok_s, ent_m, pre_s, pre_m,
                                                 sb, mb, c2t, e2t, pta_g, es_g);
    merge_loss_kernel<<<16, 512, 0, stream>>>(r, pta_g, es_g, c2t, spans, labels, msum, out, argb);
    if (r < R_-1){
      curr_kernel<<<(M_*H_/8)/256, 256, 0, stream>>>(tok_bf, argb, currbf);
      gemm_kernel<<<dim3(N_/128, M_/128), 256, 0, stream>>>(currbf, preA, w_t, ab, preB);
      dots_pre_kernel<<<(M_*64)/256, 256, 0, stream>>>(preB, sw, mw, pre_s, pre_m);
      uint16_t* tmp = preA; preA = preB; preB = tmp;
    }
  }
}

// Round 3
// 262.414 us; speedup vs baseline: 5.8899x; 2.7775x over previous
//
#include <hip/hip_runtime.h>
#include <stdint.h>

// Problem dims
#define R_ 8
#define B_ 16
#define S_ 512
#define H_ 1024
#define E_ 32
#define P_ 4
#define M_ (B_*S_)          // 8192 rows

// ---------------- mask sum (token_mask.sum()) ----------------
__global__ void masksum_kernel(const float* __restrict__ tm, float* __restrict__ msum){
  __shared__ float red[16];
  int t = threadIdx.x;
  float s = 0.f;
  for (int i = t; i < B_*S_; i += 1024) s += tm[i];
  #pragma unroll
  for (int m = 32; m >= 1; m >>= 1) s += __shfl_xor(s, m, 64);
  if ((t & 63) == 0) red[t >> 6] = s;
  __syncthreads();
  if (t == 0){ float tot = 0.f; for (int i = 0; i < 16; i++) tot += red[i]; msum[0] = tot; }
}

// ---------------- vec chain: a_{k+1} = W2 a_k, v_k = W1 a_k, beta_k = b.a_k ----
// aw: answer_w [2H][H] row-major. W1 = rows [0,H), W2 = rows [H,2H).
// a_s/a_m: [8][H]; slot 0 unused (a_0 comes from sw/mw directly).
// V: [14][H]  (q=0..6 -> v^s_k, q=7..13 -> v^m_k)
// betas: [16]  (0..7 s, 8..15 m)
__global__ __launch_bounds__(256) void vec_chain_kernel(
    int k, const float* __restrict__ aw, const float* __restrict__ ab,
    const float* __restrict__ sw, const float* __restrict__ mw,
    float* __restrict__ a_s, float* __restrict__ a_m,
    float* __restrict__ V, float* __restrict__ betas)
{
  int w = (int)((blockIdx.x * blockDim.x + threadIdx.x) >> 6);
  int lane = threadIdx.x & 63;
  const float* as_k = (k == 0) ? (sw + 2*H_) : (a_s + (size_t)k*H_);
  const float* am_k = (k == 0) ? (mw + 2*H_) : (a_m + (size_t)k*H_);
  if (w < H_){
    const float* w1 = aw + (size_t)w * H_;
    const float* w2 = aw + (size_t)(H_ + w) * H_;
    float vs = 0.f, vm = 0.f, ns = 0.f, nm = 0.f;
    #pragma unroll
    for (int i = 0; i < 4; i++){
      int c = i*256 + lane*4;
      float4 r1 = *(const float4*)(w1 + c);
      float4 r2 = *(const float4*)(w2 + c);
      float4 xs = *(const float4*)(as_k + c);
      float4 xm = *(const float4*)(am_k + c);
      vs += r1.x*xs.x + r1.y*xs.y + r1.z*xs.z + r1.w*xs.w;
      vm += r1.x*xm.x + r1.y*xm.y + r1.z*xm.z + r1.w*xm.w;
      ns += r2.x*xs.x + r2.y*xs.y + r2.z*xs.z + r2.w*xs.w;
      nm += r2.x*xm.x + r2.y*xm.y + r2.z*xm.z + r2.w*xm.w;
    }
    #pragma unroll
    for (int m = 32; m >= 1; m >>= 1){
      vs += __shfl_xor(vs, m, 64); vm += __shfl_xor(vm, m, 64);
      ns += __shfl_xor(ns, m, 64); nm += __shfl_xor(nm, m, 64);
    }
    if (lane == 0){
      V[(size_t)k*H_ + w]       = vs;
      V[(size_t)(7 + k)*H_ + w] = vm;
      a_s[(size_t)(k+1)*H_ + w] = ns;
      a_m[(size_t)(k+1)*H_ + w] = nm;
    }
  } else if (w == H_ || w == H_ + 1){
    const float* av = (w == H_) ? as_k : am_k;
    float d = 0.f;
    #pragma unroll
    for (int i = 0; i < 4; i++){
      int c = i*256 + lane*4;
      float4 r1 = *(const float4*)(ab + c);
      float4 xs = *(const float4*)(av + c);
      d += r1.x*xs.x + r1.y*xs.y + r1.z*xs.z + r1.w*xs.w;
    }
    #pragma unroll
    for (int m = 32; m >= 1; m >>= 1) d += __shfl_xor(d, m, 64);
    if (lane == 0) betas[(w == H_ ? 0 : 8) + k] = d;
  }
}

// ---------------- fused dots: sr_s/sr_m, tok_s + G[14], ent_m ----
// waves: [0,65536) sr rows; [65536,73728) tok rows (15 dots); [73728,81920) ent rows
__global__ void dots_kernel(const float* __restrict__ sr, const float* __restrict__ tok,
                            const float* __restrict__ ent, const float* __restrict__ sw,
                            const float* __restrict__ mw, const float* __restrict__ V,
                            float* __restrict__ sr_s, float* __restrict__ sr_m,
                            float* __restrict__ tok_s, float* __restrict__ ent_m,
                            float* __restrict__ G){
  int w = (int)((blockIdx.x * blockDim.x + threadIdx.x) >> 6);
  int lane = threadIdx.x & 63;
  if (w < R_*B_*S_){
    const float* rp = sr + (size_t)w * H_;
    float a0 = 0.f, a1 = 0.f;
    #pragma unroll
    for (int i = 0; i < 4; i++){
      int c = i*256 + lane*4;
      float4 v  = *(const float4*)(rp + c);
      float4 ws = *(const float4*)(sw + c);
      float4 wm = *(const float4*)(mw + c);
      a0 += v.x*ws.x + v.y*ws.y + v.z*ws.z + v.w*ws.w;
      a1 += v.x*wm.x + v.y*wm.y + v.z*wm.z + v.w*wm.w;
    }
    #pragma unroll
    for (int m = 32; m >= 1; m >>= 1){ a0 += __shfl_xor(a0, m, 64); a1 += __shfl_xor(a1, m, 64); }
    if (lane == 0){ sr_s[w] = a0; sr_m[w] = a1; }
  } else if (w < R_*B_*S_ + B_*S_){
    int rr = w - R_*B_*S_;
    const float* rp = tok + (size_t)rr * H_;
    float acc[15] = {};
    #pragma unroll
    for (int i = 0; i < 4; i++){
      int c = i*256 + lane*4;
      float4 v  = *(const float4*)(rp + c);
      float4 ws = *(const float4*)(sw + H_ + c);
      acc[0] += v.x*ws.x + v.y*ws.y + v.z*ws.z + v.w*ws.w;
      #pragma unroll
      for (int q = 0; q < 14; q++){
        float4 vv = *(const float4*)(V + (size_t)q*H_ + c);
        acc[q+1] += v.x*vv.x + v.y*vv.y + v.z*vv.z + v.w*vv.w;
      }
    }
    #pragma unroll
    for (int q = 0; q < 15; q++)
      #pragma unroll
      for (int m = 32; m >= 1; m >>= 1) acc[q] += __shfl_xor(acc[q], m, 64);
    if (lane == 0){
      tok_s[rr] = acc[0];
      #pragma unroll
      for (int q = 0; q < 14; q++) G[(size_t)q*M_ + rr] = acc[q+1];
    }
  } else if (w < R_*B_*S_ + 2*B_*S_){
    int rr = w - R_*B_*S_ - B_*S_;
    const float* rp = ent + (size_t)rr * H_;
    float a0 = 0.f;
    #pragma unroll
    for (int i = 0; i < 4; i++){
      int c = i*256 + lane*4;
      float4 v  = *(const float4*)(rp + c);
      float4 wm = *(const float4*)(mw + H_ + c);
      a0 += v.x*wm.x + v.y*wm.y + v.z*wm.z + v.w*wm.w;
    }
    #pragma unroll
    for (int m = 32; m >= 1; m >>= 1) a0 += __shfl_xor(a0, m, 64);
    if (lane == 0) ent_m[rr] = a0;
  }
}

// ---------------- per-role fused kernel ----------------------
// grid 16 blocks (one per batch row b) x 512 threads (one per s).
// pre_s/pre_m reconstructed from arg history via the G recurrence.
__global__ __launch_bounds__(512) void role_kernel(
    int r,
    const float* __restrict__ sr_s, const float* __restrict__ sr_m,
    const float* __restrict__ tok_s, const float* __restrict__ ent_m,
    const float* __restrict__ G, const float* __restrict__ betas,
    float* __restrict__ argb,
    const float* __restrict__ sb, const float* __restrict__ mb,
    const int* __restrict__ c2t, const int* __restrict__ e2t,
    const int* __restrict__ spans, const int* __restrict__ labels,
    const float* __restrict__ msum, float* __restrict__ out)
{
  __shared__ float pta[S_];
  __shared__ float es[E_];
  __shared__ int   spn[E_*P_*2];
  __shared__ float merged[S_];
  __shared__ float red[8];
  const int b = blockIdx.x;
  const int t = threadIdx.x;     // position s

  pta[t] = 0.f;
  if (t < E_) es[t] = 0.f;
  if (t < E_*P_*2) spn[t] = spans[b*(E_*P_*2) + t];
  __syncthreads();

  // beta prefix (same constant for every row/pos)
  float bsum_s = 0.f, bsum_m = 0.f;
  for (int k = 0; k < r; k++){ bsum_s += betas[k]; bsum_m += betas[8 + k]; }
  const float sbv = sb[0] + bsum_s, mbv = mb[0] + bsum_m;

  // logits for ALL batch rows at position t (softmax over batch axis)
  float sl[B_], ml[B_];
  float smax = -1e30f, mmax = -1e30f;
  #pragma unroll
  for (int bb = 0; bb < B_; bb++){
    int bs = bb*S_ + t;
    float ps = 0.f, pm = 0.f;
    for (int j = 0; j < r; j++){
      float aj = argb[j*M_ + bs];
      ps += aj * G[(size_t)(r-1-j)*M_ + bs];
      pm += aj * G[(size_t)(7 + r-1-j)*M_ + bs];
    }
    float x = sr_s[(size_t)(r*B_ + bb)*S_ + t] + tok_s[bs] + ps + sbv;
    float y = sr_m[(size_t)(r*B_ + bb)*S_ + t] + ent_m[bs] + pm + mbv;
    sl[bb] = x; ml[bb] = y;
    smax = fmaxf(smax, x); mmax = fmaxf(mmax, y);
  }
  float ssum = 0.f, msv = 0.f;
  #pragma unroll
  for (int bb = 0; bb < B_; bb++){ ssum += __expf(sl[bb]-smax); msv += __expf(ml[bb]-mmax); }

  // scatter only this block's batch row
  float spv = __expf(sl[b]-smax) / ssum;
  float mpv = __expf(ml[b]-mmax) / msv;
  {
    int c = c2t[b*S_ + t];
    if (c >= 0) atomicAdd(&pta[c], spv);
    int e = e2t[b*S_ + t];
    if (e >= 0) atomicAdd(&es[e], mpv);
  }
  __syncthreads();

  // span coverage + max-merge
  float pei = 0.f;
  #pragma unroll
  for (int e = 0; e < E_; e++){
    float sc = es[e];
    #pragma unroll
    for (int p = 0; p < P_; p++){
      int st = spn[e*8 + p*2], en = spn[e*8 + p*2 + 1];
      if (t >= st && t < en) pei += sc;
    }
  }
  float m = fmaxf(pta[t], pei);
  merged[t] = m;
  out[1 + (size_t)r*M_ + b*S_ + t] = m;
  __syncthreads();

  // arg gather (input for later roles)
  {
    int c = c2t[b*S_ + t];
    argb[(size_t)r*M_ + b*S_ + t] = (c >= 0) ? merged[c] : 0.f;
  }

  // CE loss for this row
  int wid = t >> 6, lane = t & 63;
  float mx = m;
  #pragma unroll
  for (int k = 32; k >= 1; k >>= 1) mx = fmaxf(mx, __shfl_xor(mx, k, 64));
  if (lane == 0) red[wid] = mx;
  __syncthreads();
  float gmx = red[0];
  #pragma unroll
  for (int i = 1; i < 8; i++) gmx = fmaxf(gmx, red[i]);
  float se = __expf(m - gmx);
  #pragma unroll
  for (int k = 32; k >= 1; k >>= 1) se += __shfl_xor(se, k, 64);
  __syncthreads();
  if (lane == 0) red[wid] = se;
  __syncthreads();
  if (t == 0){
    float tot = 0.f;
    #pragma unroll
    for (int i = 0; i < 8; i++) tot += red[i];
    float lse = gmx + __logf(tot);
    int lbl = labels[r*B_ + b];
    float nll = lse - merged[lbl];
    atomicAdd(out, nll * msum[0] * (1.0f/16.0f));
  }
}

extern "C" void kernel_launch(void* const* d_in, const int* in_sizes, int n_in,
                              void* d_out, int out_size, void* d_ws, size_t ws_size,
                              hipStream_t stream){
  (void)in_sizes; (void)n_in; (void)out_size; (void)ws_size;
  const int*   labels = (const int*)  d_in[0];
  const float* sr     = (const float*)d_in[1];
  const float* tok    = (const float*)d_in[2];
  const float* ent    = (const float*)d_in[3];
  const float* tmask  = (const float*)d_in[4];
  // d_in[5] entity_mask unused by reference
  const int*   spans  = (const int*)  d_in[6];
  const int*   c2t    = (const int*)  d_in[7];
  const int*   e2t    = (const int*)  d_in[8];
  const float* sw     = (const float*)d_in[9];
  const float* sb     = (const float*)d_in[10];
  const float* mw     = (const float*)d_in[11];
  const float* mb     = (const float*)d_in[12];
  const float* aw     = (const float*)d_in[13];
  const float* ab     = (const float*)d_in[14];
  float* out = (float*)d_out;
  char*  ws  = (char*)d_ws;

  size_t o = 0;
  auto take = [&](size_t bytes){ size_t c = o; o += (bytes + 255) & ~(size_t)255; return c; };
  float* sr_s  = (float*)(ws + take((size_t)R_*B_*S_*4));
  float* sr_m  = (float*)(ws + take((size_t)R_*B_*S_*4));
  float* tok_s = (float*)(ws + take((size_t)B_*S_*4));
  float* ent_m = (float*)(ws + take((size_t)B_*S_*4));
  float* argb  = (float*)(ws + take((size_t)R_*M_*4));
  float* a_s   = (float*)(ws + take((size_t)8*H_*4));
  float* a_m   = (float*)(ws + take((size_t)8*H_*4));
  float* V     = (float*)(ws + take((size_t)14*H_*4));
  float* betas = (float*)(ws + take(64));
  float* G     = (float*)(ws + take((size_t)14*M_*4));
  float* msum  = (float*)(ws + take(256));

  hipMemsetAsync(out, 0, sizeof(float), stream);   // loss accumulator

  masksum_kernel<<<1, 1024, 0, stream>>>(tmask, msum);
  for (int k = 0; k < 7; k++)
    vec_chain_kernel<<<257, 256, 0, stream>>>(k, aw, ab, sw, mw, a_s, a_m, V, betas);
  {
    int waves = R_*B_*S_ + 2*B_*S_;                // 81920
    dots_kernel<<<waves/4, 256, 0, stream>>>(sr, tok, ent, sw, mw, V,
                                             sr_s, sr_m, tok_s, ent_m, G);
  }
  for (int r = 0; r < R_; r++){
    role_kernel<<<16, 512, 0, stream>>>(r, sr_s, sr_m, tok_s, ent_m, G, betas, argb,
                                        sb, mb, c2t, e2t, spans, labels, msum, out);
  }
}